// Round 11
// baseline (47.913 us; speedup 1.0000x reference)
//
#include <hip/hip_runtime.h>
#include <math.h>

#define GN 8192
#define BN 2
#define HN 256
#define WN 256
#define FRONT_K 8
#define EPS_T 1e-8f
#define ALPHA_T (1.0f / 255.0f)
#define TDIM 32                 // 32x32 tiles of 8x8 px per batch
#define NTILE (TDIM * TDIM)
#define CAP 256                 // per-tile list cap (mean ~54)

// ---------------------------------------------------------------------------
// Kernel 0: clear per-tile counters (BN*NTILE = 2048 u32).
// ---------------------------------------------------------------------------
__global__ __launch_bounds__(64) void pgr_clear(unsigned* __restrict__ cur)
{
    cur[blockIdx.x * 64 + threadIdx.x] = 0u;
}

// ---------------------------------------------------------------------------
// Kernel 1: prep + binning. One thread per (batch, gaussian). r11: the bin
// slot holds the FULL record {key, A, B, C} (44B), not a u32 index — the
// raster then has ZERO dependent gathers (its loads are all coalesced
// slot-tid reads issued in parallel). Append order irrelevant: raster
// rank-sorts each list by the (depth,idx) key, which is the stable argsort.
// ---------------------------------------------------------------------------
__global__ __launch_bounds__(64) void pgr_prep(
    const float* __restrict__ means2d, const float* __restrict__ conics,
    const float* __restrict__ colors, const float* __restrict__ opac,
    const float* __restrict__ depths,
    unsigned* __restrict__ cur, unsigned long long* __restrict__ kent,
    float4* __restrict__ recA, float4* __restrict__ recB,
    float* __restrict__ recC)
{
    int g = blockIdx.x * 64 + threadIdx.x;       // [0, BN*GN)
    int b = g >> 13, i = g & (GN - 1);
    float2 mxy = reinterpret_cast<const float2*>(means2d)[g];
    float mx = mxy.x, my = mxy.y;
    float ca = conics[3 * g], cb = conics[3 * g + 1], cc = conics[3 * g + 2];
    float r = colors[3 * g], g2 = colors[3 * g + 1], b3 = colors[3 * g + 2];
    float op = opac[g];
    float dep = depths[g];

    // alpha >= 1/255  <=>  sigma <= ln(255*op); conservative margins
    // (__logf rel-err ~1e-7 absorbed by +1e-4 / +0.02px slack)
    float s = (op > 0.f) ? (__logf(255.0f * op) + 1e-4f) : -1.0f;
    if (s < 0.f) return;                          // alpha < 1/255 everywhere
    float det = fmaxf(ca * cc - cb * cb, 1e-12f);
    float dxm = sqrtf(2.f * s * cc / det) + 0.02f;
    float dym = sqrtf(2.f * s * ca / det) + 0.02f;
    int x0 = (int)floorf(mx - dxm - 0.5f), x1 = (int)ceilf(mx + dxm - 0.5f);
    int y0 = (int)floorf(my - dym - 0.5f), y1 = (int)ceilf(my + dym - 0.5f);
    if (x1 < 0 || x0 > WN - 1 || y1 < 0 || y0 > HN - 1) return;
    x0 = max(x0, 0); x1 = min(x1, WN - 1);
    y0 = max(y0, 0); y1 = min(y1, HN - 1);
    int tx0 = x0 >> 3, tx1 = x1 >> 3, ty0 = y0 >> 3, ty1 = y1 >> 3;

    unsigned long long key =
        ((unsigned long long)__float_as_uint(dep) << 13) | (unsigned)i;
    float4 A = make_float4(mx, my, ca, cb);
    float4 B = make_float4(cc, op, r, g2);

    for (int ty = ty0; ty <= ty1; ++ty)
        for (int tx = tx0; tx <= tx1; ++tx) {
            int t = b * NTILE + ty * TDIM + tx;
            unsigned pos = atomicAdd(&cur[t], 1u);
            if (pos < CAP) {
                int sl = t * CAP + (int)pos;
                kent[sl] = key;
                recA[sl] = A;
                recB[sl] = B;
                recC[sl] = b3;
            }
        }
}

// rank of key k among s_key[0..L): broadcast LDS reads, no barriers, pipelined
__device__ __forceinline__ int rank_of(const unsigned long long* s_key,
                                       unsigned long long k, int L)
{
    int rank = 0, j = 0;
    for (; j + 4 <= L; j += 4) {
        unsigned long long k0 = s_key[j], k1 = s_key[j + 1];
        unsigned long long k2 = s_key[j + 2], k3 = s_key[j + 3];
        rank += (int)(k0 < k) + (int)(k1 < k) + (int)(k2 < k) + (int)(k3 < k);
    }
    for (; j < L; ++j) rank += (int)(s_key[j] < k);
    return rank;
}

// ---------------------------------------------------------------------------
// Kernel 2: raster. 64 threads = 1 wave = one 8x8 tile. r11: all inputs are
// coalesced slot-tid bin reads issued in parallel at block start (no gather
// chain). Lane tid rank-sorts its slot's key via broadcast LDS reads,
// scatters its record to LDS slot rank == exact stable depth order, then
// composites in 8-wide ILP batches (__expf; exact reference gate chain).
// ---------------------------------------------------------------------------
__global__ __launch_bounds__(64) void pgr_raster(
    const unsigned* __restrict__ cur, const unsigned long long* __restrict__ kent,
    const float4* __restrict__ recA, const float4* __restrict__ recB,
    const float* __restrict__ recC, float* __restrict__ out)
{
    const int b = blockIdx.z;
    const int t = b * NTILE + blockIdx.y * TDIM + blockIdx.x;
    const int tid = threadIdx.x;
    const int tx0 = blockIdx.x * 8, ty0 = blockIdx.y * 8;
    const int lx = tid & 7, ly = tid >> 3;
    const float px = tx0 + lx + 0.5f, py = ty0 + ly + 0.5f;

    __shared__ unsigned long long s_key[CAP];
    __shared__ float4 s_d0[CAP], s_d1[CAP];
    __shared__ float s_d2[CAP];

    // parallel, coalesced, speculative loads (slot tid always allocated;
    // values for tid >= L are discarded)
    const int base = t * CAP;
    unsigned long long myk = kent[base + tid];
    float4 r0 = recA[base + tid];
    float4 r1 = recB[base + tid];
    float r2 = recC[base + tid];
    const int L = min((int)cur[t], CAP);

    if (tid < L) s_key[tid] = myk;
    for (int i = 64 + tid; i < L; i += 64)         // uncommon: L > 64
        s_key[i] = kent[base + i];
    __syncthreads();

    if (tid < L) {
        int rank = rank_of(s_key, myk, L);
        s_d0[rank] = r0; s_d1[rank] = r1; s_d2[rank] = r2;
    }
    for (int i = 64 + tid; i < L; i += 64) {       // uncommon: L > 64
        int rank = rank_of(s_key, s_key[i], L);
        s_d0[rank] = recA[base + i];
        s_d1[rank] = recB[base + i];
        s_d2[rank] = recC[base + i];
    }
    __syncthreads();

    float accR = 0.f, accG = 0.f, accB = 0.f, T = 1.f;
    int count = 0;
    bool done = false;

    for (int i0 = 0; i0 < L; i0 += 8) {
        if (__all((int)done)) break;
        float alpha[8], colR[8], colG[8], colB[8];
        bool valid[8];
        // phase 1: 8 independent loads + sigma + exp (ILP hides LDS/exp latency)
        #pragma unroll
        for (int k = 0; k < 8; ++k) {
            int idx = i0 + k;
            bool act = (idx < L) && !done;
            int ii = act ? idx : i0;               // clamped, discarded
            float4 d0 = s_d0[ii];
            float4 d1 = s_d1[ii];
            float dx = __fsub_rn(px, d0.x);
            float dy = __fsub_rn(py, d0.y);
            // sigma = 0.5*((a*dx)*dx + (c*dy)*dy) + (b*dx)*dy (numpy order)
            float t1 = __fmul_rn(__fmul_rn(d0.z, dx), dx);
            float t2 = __fmul_rn(__fmul_rn(d1.x, dy), dy);
            float sigma = __fadd_rn(__fmul_rn(0.5f, __fadd_rn(t1, t2)),
                                    __fmul_rn(__fmul_rn(d0.w, dx), dy));
            bool v = act && sigma >= 0.f && sigma <= 5.55f;  // e^-5.55 < 1/255
            float al = v ? fminf(__fmul_rn(d1.y, __expf(-sigma)), 0.999f) : 0.f;
            valid[k] = v && (al >= ALPHA_T);
            alpha[k] = al;
            colR[k] = d1.z; colG[k] = d1.w; colB[k] = s_d2[ii];
        }
        // phase 2: serial front-to-back blend (exact reference semantics)
        #pragma unroll
        for (int k = 0; k < 8; ++k) {
            if (valid[k] && !done) {
                float al = alpha[k];
                if (T > EPS_T) {
                    float w = __fmul_rn(T, al);
                    accR += w * colR[k];
                    accG += w * colG[k];
                    accB += w * colB[k];
                }
                T = __fmul_rn(T, __fsub_rn(1.f, al));
                count++;
                if (count >= FRONT_K || T <= EPS_T) done = true;
            }
        }
    }

    int o = ((b * HN + (ty0 + ly)) * WN + (tx0 + lx)) * 3;
    out[o] = accR;
    out[o + 1] = accG;
    out[o + 2] = accB;     // bg == 0, so output is accum only
}

extern "C" void kernel_launch(void* const* d_in, const int* in_sizes, int n_in,
                              void* d_out, int out_size, void* d_ws, size_t ws_size,
                              hipStream_t stream) {
    const float* means2d = (const float*)d_in[0];
    const float* conics  = (const float*)d_in[1];
    const float* colors  = (const float*)d_in[2];
    const float* opac    = (const float*)d_in[3];
    const float* depths  = (const float*)d_in[4];
    float* out = (float*)d_out;

    const int NSLOT = BN * NTILE * CAP;                   // 524288 slots
    float4*             recA = (float4*)d_ws;             //  8 MB
    float4*             recB = recA + NSLOT;              //  8 MB
    unsigned long long* kent = (unsigned long long*)(recB + NSLOT);  // 4 MB
    float*              recC = (float*)(kent + NSLOT);    //  2 MB
    unsigned*           cur  = (unsigned*)(recC + NSLOT); //  8 KB

    pgr_clear<<<(BN * NTILE) / 64, 64, 0, stream>>>(cur);
    pgr_prep<<<(BN * GN) / 64, 64, 0, stream>>>(means2d, conics, colors, opac,
                                                depths, cur, kent, recA, recB, recC);
    pgr_raster<<<dim3(TDIM, TDIM, BN), 64, 0, stream>>>(
        cur, kent, recA, recB, recC, out);
}

// Round 12
// 47.396 us; speedup vs baseline: 1.0109x; 1.0109x over previous
//
#include <hip/hip_runtime.h>
#include <math.h>

#define GN 8192
#define BN 2
#define HN 256
#define WN 256
#define FRONT_K 8
#define EPS_T 1e-8f
#define ALPHA_T (1.0f / 255.0f)
#define TDIM 32                 // 32x32 tiles of 8x8 px per batch
#define NTILE (TDIM * TDIM)
#define CAP 256                 // per-tile list cap (max observed L <= 224)

// ---------------------------------------------------------------------------
// Kernel 0: clear per-tile counters (BN*NTILE = 2048 u32).
// ---------------------------------------------------------------------------
__global__ __launch_bounds__(64) void pgr_clear(unsigned* __restrict__ cur)
{
    cur[blockIdx.x * 64 + threadIdx.x] = 0u;
}

// ---------------------------------------------------------------------------
// Kernel 1: prep + binning (r11 fat-record form). One thread per gaussian:
// bin slot holds the FULL record {key, A, B, C} so the raster's loads are
// all coalesced slot-tid reads. Append order irrelevant (raster rank-sorts
// by the unique (depth,idx) key == reference's stable depth argsort).
// ---------------------------------------------------------------------------
__global__ __launch_bounds__(64) void pgr_prep(
    const float* __restrict__ means2d, const float* __restrict__ conics,
    const float* __restrict__ colors, const float* __restrict__ opac,
    const float* __restrict__ depths,
    unsigned* __restrict__ cur, unsigned long long* __restrict__ kent,
    float4* __restrict__ recA, float4* __restrict__ recB,
    float* __restrict__ recC)
{
    int g = blockIdx.x * 64 + threadIdx.x;       // [0, BN*GN)
    int b = g >> 13, i = g & (GN - 1);
    float2 mxy = reinterpret_cast<const float2*>(means2d)[g];
    float mx = mxy.x, my = mxy.y;
    float ca = conics[3 * g], cb = conics[3 * g + 1], cc = conics[3 * g + 2];
    float r = colors[3 * g], g2 = colors[3 * g + 1], b3 = colors[3 * g + 2];
    float op = opac[g];
    float dep = depths[g];

    // alpha >= 1/255 <=> sigma <= ln(255*op); margins absorb __logf error
    float s = (op > 0.f) ? (__logf(255.0f * op) + 1e-4f) : -1.0f;
    if (s < 0.f) return;                          // alpha < 1/255 everywhere
    float det = fmaxf(ca * cc - cb * cb, 1e-12f);
    float dxm = sqrtf(2.f * s * cc / det) + 0.02f;
    float dym = sqrtf(2.f * s * ca / det) + 0.02f;
    int x0 = (int)floorf(mx - dxm - 0.5f), x1 = (int)ceilf(mx + dxm - 0.5f);
    int y0 = (int)floorf(my - dym - 0.5f), y1 = (int)ceilf(my + dym - 0.5f);
    if (x1 < 0 || x0 > WN - 1 || y1 < 0 || y0 > HN - 1) return;
    x0 = max(x0, 0); x1 = min(x1, WN - 1);
    y0 = max(y0, 0); y1 = min(y1, HN - 1);
    int tx0 = x0 >> 3, tx1 = x1 >> 3, ty0 = y0 >> 3, ty1 = y1 >> 3;

    unsigned long long key =
        ((unsigned long long)__float_as_uint(dep) << 13) | (unsigned)i;
    float4 A = make_float4(mx, my, ca, cb);
    float4 B = make_float4(cc, op, r, g2);

    for (int ty = ty0; ty <= ty1; ++ty)
        for (int tx = tx0; tx <= tx1; ++tx) {
            int t = b * NTILE + ty * TDIM + tx;
            unsigned pos = atomicAdd(&cur[t], 1u);
            if (pos < CAP) {
                int sl = t * CAP + (int)pos;
                kent[sl] = key;
                recA[sl] = A;
                recB[sl] = B;
                recC[sl] = b3;
            }
        }
}

// rank of key k among s_key[0..L): broadcast LDS reads, no barriers, pipelined
__device__ __forceinline__ int rank_of(const unsigned long long* s_key,
                                       unsigned long long k, int L)
{
    int rank = 0, j = 0;
    for (; j + 4 <= L; j += 4) {
        unsigned long long k0 = s_key[j], k1 = s_key[j + 1];
        unsigned long long k2 = s_key[j + 2], k3 = s_key[j + 3];
        rank += (int)(k0 < k) + (int)(k1 < k) + (int)(k2 < k) + (int)(k3 < k);
    }
    for (; j < L; ++j) rank += (int)(s_key[j] < k);
    return rank;
}

// ---------------------------------------------------------------------------
// Kernel 2: raster. r12: 256 threads = 4 waves per 8x8 tile — the tile's
// LIST is split into 4 contiguous depth chunks, one per wave. kept-bit is
// compositing-state-independent, so each wave masks its chunk in parallel
// (all 64 lanes = 64 pixels); wave 0 then blends the first <=8 set bits per
// pixel in depth order (bit-identical recomputed alpha, exact ref gates).
// 2048 blocks x 4 waves = 32 waves/CU (was 8) — the latency-bound fix.
// ---------------------------------------------------------------------------
__global__ __launch_bounds__(256) void pgr_raster(
    const unsigned* __restrict__ cur, const unsigned long long* __restrict__ kent,
    const float4* __restrict__ recA, const float4* __restrict__ recB,
    const float* __restrict__ recC, float* __restrict__ out)
{
    const int b = blockIdx.z;
    const int t = b * NTILE + blockIdx.y * TDIM + blockIdx.x;
    const int tid = threadIdx.x;
    const int wave = tid >> 6, lane = tid & 63;
    const int tx0 = blockIdx.x * 8, ty0 = blockIdx.y * 8;
    const int lx = lane & 7, ly = lane >> 3;
    const float px = tx0 + lx + 0.5f, py = ty0 + ly + 0.5f;

    __shared__ unsigned long long s_key[CAP];
    __shared__ float4 s_d0[CAP], s_d1[CAP];
    __shared__ float s_d2[CAP];
    __shared__ unsigned long long s_mask[4][64];

    // one coalesced step loads all CAP slots (speculative; >=L discarded)
    const int base = t * CAP;
    unsigned long long myk = kent[base + tid];
    float4 r0 = recA[base + tid];
    float4 r1 = recB[base + tid];
    float r2 = recC[base + tid];
    const int L = min((int)cur[t], CAP);

    if (tid < L) s_key[tid] = myk;
    __syncthreads();

    if (tid < L) {
        int rank = rank_of(s_key, myk, L);     // 256 threads rank in parallel
        s_d0[rank] = r0; s_d1[rank] = r1; s_d2[rank] = r2;
    }
    __syncthreads();

    // ---- mask pass: wave w -> sorted chunk [w*chunk, min((w+1)*chunk, L)) ----
    const int chunk = (L + 3) >> 2;            // <= 64, so one u64 per pixel
    const int lo = wave * chunk, hi = min(lo + chunk, L);
    unsigned long long m = 0ull;
    for (int i0 = lo; i0 < hi; i0 += 8) {
        #pragma unroll
        for (int k = 0; k < 8; ++k) {
            int idx = i0 + k;
            bool act = idx < hi;
            int ii = act ? idx : lo;           // clamped, discarded
            float4 d0 = s_d0[ii];              // broadcast LDS reads
            float4 d1 = s_d1[ii];
            float dx = __fsub_rn(px, d0.x);
            float dy = __fsub_rn(py, d0.y);
            // sigma = 0.5*((a*dx)*dx + (c*dy)*dy) + (b*dx)*dy (numpy order)
            float t1 = __fmul_rn(__fmul_rn(d0.z, dx), dx);
            float t2 = __fmul_rn(__fmul_rn(d1.x, dy), dy);
            float sigma = __fadd_rn(__fmul_rn(0.5f, __fadd_rn(t1, t2)),
                                    __fmul_rn(__fmul_rn(d0.w, dx), dy));
            bool v = act && sigma >= 0.f && sigma <= 5.55f;  // e^-5.55 < 1/255
            float al = v ? fminf(__fmul_rn(d1.y, __expf(-sigma)), 0.999f) : 0.f;
            if (al >= ALPHA_T && v) m |= 1ull << (idx - lo);
        }
    }
    s_mask[wave][lane] = m;
    __syncthreads();

    // ---- blend (wave 0): first <=8 kept bits in depth order, exact chain ----
    if (wave == 0) {
        float accR = 0.f, accG = 0.f, accB = 0.f, T = 1.f;
        int taken = 0;
        #pragma unroll 1
        for (int w = 0; w < 4 && taken < FRONT_K; ++w) {
            unsigned long long mm = s_mask[w][lane];
            while (mm && taken < FRONT_K) {
                int bit = __builtin_ctzll(mm);
                mm &= mm - 1;
                int idx = w * chunk + bit;
                float4 d0 = s_d0[idx];
                float4 d1 = s_d1[idx];
                float dx = __fsub_rn(px, d0.x);
                float dy = __fsub_rn(py, d0.y);
                float t1 = __fmul_rn(__fmul_rn(d0.z, dx), dx);
                float t2 = __fmul_rn(__fmul_rn(d1.x, dy), dy);
                float sigma = __fadd_rn(__fmul_rn(0.5f, __fadd_rn(t1, t2)),
                                        __fmul_rn(__fmul_rn(d0.w, dx), dy));
                float al = fminf(__fmul_rn(d1.y, __expf(-sigma)), 0.999f);
                if (T > EPS_T) {                       // bit-identical recompute
                    float wgt = __fmul_rn(T, al);
                    accR += wgt * d1.z;
                    accG += wgt * d1.w;
                    accB += wgt * s_d2[idx];
                }
                T = __fmul_rn(T, __fsub_rn(1.f, al));
                ++taken;
                if (T <= EPS_T) taken = FRONT_K;       // monotone: rest are 0
            }
        }
        int o = ((b * HN + (ty0 + ly)) * WN + (tx0 + lx)) * 3;
        out[o] = accR;
        out[o + 1] = accG;
        out[o + 2] = accB;     // bg == 0, so output is accum only
    }
}

extern "C" void kernel_launch(void* const* d_in, const int* in_sizes, int n_in,
                              void* d_out, int out_size, void* d_ws, size_t ws_size,
                              hipStream_t stream) {
    const float* means2d = (const float*)d_in[0];
    const float* conics  = (const float*)d_in[1];
    const float* colors  = (const float*)d_in[2];
    const float* opac    = (const float*)d_in[3];
    const float* depths  = (const float*)d_in[4];
    float* out = (float*)d_out;

    const int NSLOT = BN * NTILE * CAP;                   // 524288 slots
    float4*             recA = (float4*)d_ws;             //  8 MB
    float4*             recB = recA + NSLOT;              //  8 MB
    unsigned long long* kent = (unsigned long long*)(recB + NSLOT);  // 4 MB
    float*              recC = (float*)(kent + NSLOT);    //  2 MB
    unsigned*           cur  = (unsigned*)(recC + NSLOT); //  8 KB

    pgr_clear<<<(BN * NTILE) / 64, 64, 0, stream>>>(cur);
    pgr_prep<<<(BN * GN) / 64, 64, 0, stream>>>(means2d, conics, colors, opac,
                                                depths, cur, kent, recA, recB, recC);
    pgr_raster<<<dim3(TDIM, TDIM, BN), 256, 0, stream>>>(
        cur, kent, recA, recB, recC, out);
}

// Round 13
// 41.260 us; speedup vs baseline: 1.1612x; 1.1487x over previous
//
#include <hip/hip_runtime.h>
#include <math.h>

#define GN 8192
#define BN 2
#define HN 256
#define WN 256
#define FRONT_K 8
#define EPS_T 1e-8f
#define ALPHA_T (1.0f / 255.0f)
#define TDIM 32                 // 32x32 tiles of 8x8 px per batch
#define NTILE (TDIM * TDIM)
#define CAP 256                 // per-tile list cap (max observed L <= 224)

// ---------------------------------------------------------------------------
// Kernel 0: clear per-tile counters (BN*NTILE = 2048 u32).
// ---------------------------------------------------------------------------
__global__ __launch_bounds__(64) void pgr_clear(unsigned* __restrict__ cur)
{
    cur[blockIdx.x * 64 + threadIdx.x] = 0u;
}

// ---------------------------------------------------------------------------
// Kernel 1: prep + binning. r13: 2048 blocks x 64 thr (8 waves/CU, was 1 —
// prep was the suspected hidden latency cost: ~7 SERIAL contended
// atomicAdd->store rounds per thread with no co-resident waves). Each 8-lane
// group owns one gaussian: bbox computed redundantly, tile-insertion loop
// DISTRIBUTED over the 8 lanes -> ~1 atomic round per lane. Bin slot holds
// the full record {key, A, B, C}; append order irrelevant (raster rank-sorts
// by the unique (depth,idx) key == reference's stable depth argsort).
// ---------------------------------------------------------------------------
__global__ __launch_bounds__(64) void pgr_prep(
    const float* __restrict__ means2d, const float* __restrict__ conics,
    const float* __restrict__ colors, const float* __restrict__ opac,
    const float* __restrict__ depths,
    unsigned* __restrict__ cur, unsigned long long* __restrict__ kent,
    float4* __restrict__ recA, float4* __restrict__ recB,
    float* __restrict__ recC)
{
    const int p = threadIdx.x >> 3;              // group 0..7
    const int q = threadIdx.x & 7;               // sublane 0..7
    int g = blockIdx.x * 8 + p;                  // [0, BN*GN)
    int b = g >> 13, i = g & (GN - 1);
    float2 mxy = reinterpret_cast<const float2*>(means2d)[g];
    float mx = mxy.x, my = mxy.y;
    float ca = conics[3 * g], cb = conics[3 * g + 1], cc = conics[3 * g + 2];
    float r = colors[3 * g], g2 = colors[3 * g + 1], b3 = colors[3 * g + 2];
    float op = opac[g];
    float dep = depths[g];

    // alpha >= 1/255 <=> sigma <= ln(255*op); margins absorb __logf error
    float s = (op > 0.f) ? (__logf(255.0f * op) + 1e-4f) : -1.0f;
    if (s < 0.f) return;                          // alpha < 1/255 everywhere
    float det = fmaxf(ca * cc - cb * cb, 1e-12f);
    float dxm = sqrtf(2.f * s * cc / det) + 0.02f;
    float dym = sqrtf(2.f * s * ca / det) + 0.02f;
    int x0 = (int)floorf(mx - dxm - 0.5f), x1 = (int)ceilf(mx + dxm - 0.5f);
    int y0 = (int)floorf(my - dym - 0.5f), y1 = (int)ceilf(my + dym - 0.5f);
    if (x1 < 0 || x0 > WN - 1 || y1 < 0 || y0 > HN - 1) return;
    x0 = max(x0, 0); x1 = min(x1, WN - 1);
    y0 = max(y0, 0); y1 = min(y1, HN - 1);
    int tx0 = x0 >> 3, tx1 = x1 >> 3, ty0 = y0 >> 3, ty1 = y1 >> 3;
    int nx = tx1 - tx0 + 1;
    int ntl = nx * (ty1 - ty0 + 1);

    unsigned long long key =
        ((unsigned long long)__float_as_uint(dep) << 13) | (unsigned)i;
    float4 A = make_float4(mx, my, ca, cb);
    float4 B = make_float4(cc, op, r, g2);

    for (int idx = q; idx < ntl; idx += 8) {      // lanes split the tile rect
        int ty = idx / nx;                        // ntl <= ~20: 1-3 iters/lane
        int tx = idx - ty * nx;
        int t = b * NTILE + (ty0 + ty) * TDIM + (tx0 + tx);
        unsigned pos = atomicAdd(&cur[t], 1u);
        if (pos < CAP) {
            int sl = t * CAP + (int)pos;
            kent[sl] = key;
            recA[sl] = A;
            recB[sl] = B;
            recC[sl] = b3;
        }
    }
}

// rank of key k among s_key[0..L): broadcast LDS reads, no barriers, pipelined
__device__ __forceinline__ int rank_of(const unsigned long long* s_key,
                                       unsigned long long k, int L)
{
    int rank = 0, j = 0;
    for (; j + 4 <= L; j += 4) {
        unsigned long long k0 = s_key[j], k1 = s_key[j + 1];
        unsigned long long k2 = s_key[j + 2], k3 = s_key[j + 3];
        rank += (int)(k0 < k) + (int)(k1 < k) + (int)(k2 < k) + (int)(k3 < k);
    }
    for (; j < L; ++j) rank += (int)(s_key[j] < k);
    return rank;
}

// ---------------------------------------------------------------------------
// Kernel 2: raster. 256 threads per 8x8 tile: all 256 bin slots staged in ONE
// coalesced round + 256-thread parallel rank-scatter (4x faster pre-phase),
// then wave 0 runs the r10-proven early-exit 8-wide composite (exact
// reference gate chain, __expf); waves 1-3 simply exit.
// ---------------------------------------------------------------------------
__global__ __launch_bounds__(256) void pgr_raster(
    const unsigned* __restrict__ cur, const unsigned long long* __restrict__ kent,
    const float4* __restrict__ recA, const float4* __restrict__ recB,
    const float* __restrict__ recC, float* __restrict__ out)
{
    const int b = blockIdx.z;
    const int t = b * NTILE + blockIdx.y * TDIM + blockIdx.x;
    const int tid = threadIdx.x;
    const int tx0 = blockIdx.x * 8, ty0 = blockIdx.y * 8;

    __shared__ unsigned long long s_key[CAP];
    __shared__ float4 s_d0[CAP], s_d1[CAP];
    __shared__ float s_d2[CAP];

    // speculative coalesced loads of slot tid (values for tid >= L discarded)
    const int base = t * CAP;
    unsigned long long myk = kent[base + tid];
    float4 r0 = recA[base + tid];
    float4 r1 = recB[base + tid];
    float r2 = recC[base + tid];
    const int L = min((int)cur[t], CAP);

    if (tid < L) s_key[tid] = myk;
    __syncthreads();

    if (tid < L) {
        int rank = rank_of(s_key, myk, L);     // 256 threads rank in parallel
        s_d0[rank] = r0; s_d1[rank] = r1; s_d2[rank] = r2;
    }
    __syncthreads();

    if (tid >= 64) return;                     // waves 1-3 done (LDS persists)

    const int lx = tid & 7, ly = tid >> 3;
    const float px = tx0 + lx + 0.5f, py = ty0 + ly + 0.5f;

    float accR = 0.f, accG = 0.f, accB = 0.f, T = 1.f;
    int count = 0;
    bool done = false;

    for (int i0 = 0; i0 < L; i0 += 8) {
        if (__all((int)done)) break;
        float alpha[8], colR[8], colG[8], colB[8];
        bool valid[8];
        // phase 1: 8 independent loads + sigma + exp (ILP hides LDS/exp latency)
        #pragma unroll
        for (int k = 0; k < 8; ++k) {
            int idx = i0 + k;
            bool act = (idx < L) && !done;
            int ii = act ? idx : i0;               // clamped, discarded
            float4 d0 = s_d0[ii];
            float4 d1 = s_d1[ii];
            float dx = __fsub_rn(px, d0.x);
            float dy = __fsub_rn(py, d0.y);
            // sigma = 0.5*((a*dx)*dx + (c*dy)*dy) + (b*dx)*dy (numpy order)
            float t1 = __fmul_rn(__fmul_rn(d0.z, dx), dx);
            float t2 = __fmul_rn(__fmul_rn(d1.x, dy), dy);
            float sigma = __fadd_rn(__fmul_rn(0.5f, __fadd_rn(t1, t2)),
                                    __fmul_rn(__fmul_rn(d0.w, dx), dy));
            bool v = act && sigma >= 0.f && sigma <= 5.55f;  // e^-5.55 < 1/255
            float al = v ? fminf(__fmul_rn(d1.y, __expf(-sigma)), 0.999f) : 0.f;
            valid[k] = v && (al >= ALPHA_T);
            alpha[k] = al;
            colR[k] = d1.z; colG[k] = d1.w; colB[k] = s_d2[ii];
        }
        // phase 2: serial front-to-back blend (exact reference semantics)
        #pragma unroll
        for (int k = 0; k < 8; ++k) {
            if (valid[k] && !done) {
                float al = alpha[k];
                if (T > EPS_T) {
                    float w = __fmul_rn(T, al);
                    accR += w * colR[k];
                    accG += w * colG[k];
                    accB += w * colB[k];
                }
                T = __fmul_rn(T, __fsub_rn(1.f, al));
                count++;
                if (count >= FRONT_K || T <= EPS_T) done = true;
            }
        }
    }

    int o = ((b * HN + (ty0 + ly)) * WN + (tx0 + lx)) * 3;
    out[o] = accR;
    out[o + 1] = accG;
    out[o + 2] = accB;     // bg == 0, so output is accum only
}

extern "C" void kernel_launch(void* const* d_in, const int* in_sizes, int n_in,
                              void* d_out, int out_size, void* d_ws, size_t ws_size,
                              hipStream_t stream) {
    const float* means2d = (const float*)d_in[0];
    const float* conics  = (const float*)d_in[1];
    const float* colors  = (const float*)d_in[2];
    const float* opac    = (const float*)d_in[3];
    const float* depths  = (const float*)d_in[4];
    float* out = (float*)d_out;

    const int NSLOT = BN * NTILE * CAP;                   // 524288 slots
    float4*             recA = (float4*)d_ws;             //  8 MB
    float4*             recB = recA + NSLOT;              //  8 MB
    unsigned long long* kent = (unsigned long long*)(recB + NSLOT);  // 4 MB
    float*              recC = (float*)(kent + NSLOT);    //  2 MB
    unsigned*           cur  = (unsigned*)(recC + NSLOT); //  8 KB

    pgr_clear<<<(BN * NTILE) / 64, 64, 0, stream>>>(cur);
    pgr_prep<<<(BN * GN) / 8, 64, 0, stream>>>(means2d, conics, colors, opac,
                                               depths, cur, kent, recA, recB, recC);
    pgr_raster<<<dim3(TDIM, TDIM, BN), 256, 0, stream>>>(
        cur, kent, recA, recB, recC, out);
}

// Round 15
// 39.059 us; speedup vs baseline: 1.2267x; 1.0564x over previous
//
#include <hip/hip_runtime.h>
#include <math.h>

#define GN 8192
#define BN 2
#define HN 256
#define WN 256
#define FRONT_K 8
#define EPS_T 1e-8f
#define ALPHA_T (1.0f / 255.0f)
#define TDIM 32                 // 32x32 tiles of 8x8 px per batch
#define NTILE (TDIM * TDIM)
#define CAP 256                 // per-tile list cap (max observed L <= 224)

// ---------------------------------------------------------------------------
// Kernel 0: clear per-tile counters (BN*NTILE = 2048 u32).
// ---------------------------------------------------------------------------
__global__ __launch_bounds__(64) void pgr_clear(unsigned* __restrict__ cur)
{
    cur[blockIdx.x * 64 + threadIdx.x] = 0u;
}

// ---------------------------------------------------------------------------
// Kernel 1: prep + binning. r15: back to u32-INDEX bins (r10 form — measured
// faster than fat-record bins, and cuts scattered store traffic 10x plus the
// cross-XCD L2 writeback volume at the kernel boundary). Per-gaussian record
// {dat0,dat1,dat2,key} written once, coalesced. 8 lanes per gaussian, the
// tile-insertion loop split over lanes (r13's proven prep parallelization).
// ---------------------------------------------------------------------------
__global__ __launch_bounds__(64) void pgr_prep(
    const float* __restrict__ means2d, const float* __restrict__ conics,
    const float* __restrict__ colors, const float* __restrict__ opac,
    const float* __restrict__ depths,
    float4* __restrict__ dat0, float4* __restrict__ dat1,
    float* __restrict__ dat2, unsigned long long* __restrict__ kdat,
    unsigned* __restrict__ cur, unsigned* __restrict__ ent)
{
    const int p = threadIdx.x >> 3;              // group 0..7
    const int q = threadIdx.x & 7;               // sublane 0..7
    int g = blockIdx.x * 8 + p;                  // [0, BN*GN)
    int b = g >> 13, i = g & (GN - 1);
    float2 mxy = reinterpret_cast<const float2*>(means2d)[g];
    float mx = mxy.x, my = mxy.y;
    float ca = conics[3 * g], cb = conics[3 * g + 1], cc = conics[3 * g + 2];
    float r = colors[3 * g], g2 = colors[3 * g + 1], b3 = colors[3 * g + 2];
    float op = opac[g];
    float dep = depths[g];

    if (q == 0) {                                 // coalesced per-gaussian record
        dat0[g] = make_float4(mx, my, ca, cb);
        dat1[g] = make_float4(cc, op, r, g2);
        dat2[g] = b3;
        kdat[g] = ((unsigned long long)__float_as_uint(dep) << 13) | (unsigned)i;
    }

    // alpha >= 1/255 <=> sigma <= ln(255*op); margins absorb __logf error
    float s = (op > 0.f) ? (__logf(255.0f * op) + 1e-4f) : -1.0f;
    if (s < 0.f) return;                          // alpha < 1/255 everywhere
    float det = fmaxf(ca * cc - cb * cb, 1e-12f);
    float dxm = sqrtf(2.f * s * cc / det) + 0.02f;
    float dym = sqrtf(2.f * s * ca / det) + 0.02f;
    int x0 = (int)floorf(mx - dxm - 0.5f), x1 = (int)ceilf(mx + dxm - 0.5f);
    int y0 = (int)floorf(my - dym - 0.5f), y1 = (int)ceilf(my + dym - 0.5f);
    if (x1 < 0 || x0 > WN - 1 || y1 < 0 || y0 > HN - 1) return;
    x0 = max(x0, 0); x1 = min(x1, WN - 1);
    y0 = max(y0, 0); y1 = min(y1, HN - 1);
    int tx0 = x0 >> 3, tx1 = x1 >> 3, ty0 = y0 >> 3, ty1 = y1 >> 3;
    int nx = tx1 - tx0 + 1;
    int ntl = nx * (ty1 - ty0 + 1);

    for (int idx = q; idx < ntl; idx += 8) {      // lanes split the tile rect
        int ty = idx / nx;
        int tx = idx - ty * nx;
        int t = b * NTILE + (ty0 + ty) * TDIM + (tx0 + tx);
        unsigned pos = atomicAdd(&cur[t], 1u);
        if (pos < CAP) ent[t * CAP + (int)pos] = (unsigned)i;
    }
}

// rank of key k among s_key[0..L): broadcast LDS reads, no barriers, pipelined
__device__ __forceinline__ int rank_of(const unsigned long long* s_key,
                                       unsigned long long k, int L)
{
    int rank = 0, j = 0;
    for (; j + 4 <= L; j += 4) {
        unsigned long long k0 = s_key[j], k1 = s_key[j + 1];
        unsigned long long k2 = s_key[j + 2], k3 = s_key[j + 3];
        rank += (int)(k0 < k) + (int)(k1 < k) + (int)(k2 < k) + (int)(k3 < k);
    }
    for (; j < L; ++j) rank += (int)(s_key[j] < k);
    return rank;
}

// ---------------------------------------------------------------------------
// Kernel 2: raster. 256 threads per 8x8 tile. tid<L loads its bin index and
// gathers the 4 per-gaussian record parts (independent gathers, issued
// together; all loads GATED on L — r13 speculatively read all 256 slots =
// 22MB/replay of dead traffic). 256-thread parallel rank-scatter, then wave 0
// runs the proven early-exit 8-wide __expf composite; waves 1-3 exit.
// ---------------------------------------------------------------------------
__global__ __launch_bounds__(256) void pgr_raster(
    const float4* __restrict__ dat0, const float4* __restrict__ dat1,
    const float* __restrict__ dat2, const unsigned long long* __restrict__ kdat,
    const unsigned* __restrict__ cur, const unsigned* __restrict__ ent,
    float* __restrict__ out)
{
    const int b = blockIdx.z;
    const int t = b * NTILE + blockIdx.y * TDIM + blockIdx.x;
    const int tid = threadIdx.x;
    const int tx0 = blockIdx.x * 8, ty0 = blockIdx.y * 8;
    const int bG = b * GN;

    __shared__ unsigned long long s_key[CAP];
    __shared__ float4 s_d0[CAP], s_d1[CAP];
    __shared__ float s_d2[CAP];

    const int base = t * CAP;
    const int L = min((int)cur[t], CAP);

    unsigned long long myk = 0;
    float4 r0, r1;
    float r2 = 0.f;
    if (tid < L) {
        int idx = bG + (int)ent[base + tid];
        myk = kdat[idx];                         // 4 independent gathers
        r0 = dat0[idx];
        r1 = dat1[idx];
        r2 = dat2[idx];
        s_key[tid] = myk;
    }
    __syncthreads();

    if (tid < L) {
        int rank = rank_of(s_key, myk, L);       // 256 threads rank in parallel
        s_d0[rank] = r0; s_d1[rank] = r1; s_d2[rank] = r2;
    }
    __syncthreads();

    if (tid >= 64) return;                       // waves 1-3 done (LDS persists)

    const int lx = tid & 7, ly = tid >> 3;
    const float px = tx0 + lx + 0.5f, py = ty0 + ly + 0.5f;

    float accR = 0.f, accG = 0.f, accB = 0.f, T = 1.f;
    int count = 0;
    bool done = false;

    for (int i0 = 0; i0 < L; i0 += 8) {
        if (__all((int)done)) break;
        float alpha[8], colR[8], colG[8], colB[8];
        bool valid[8];
        // phase 1: 8 independent loads + sigma + exp (ILP hides LDS/exp latency)
        #pragma unroll
        for (int k = 0; k < 8; ++k) {
            int idx = i0 + k;
            bool act = (idx < L) && !done;
            int ii = act ? idx : i0;               // clamped, discarded
            float4 d0 = s_d0[ii];
            float4 d1 = s_d1[ii];
            float dx = __fsub_rn(px, d0.x);
            float dy = __fsub_rn(py, d0.y);
            // sigma = 0.5*((a*dx)*dx + (c*dy)*dy) + (b*dx)*dy (numpy order)
            float t1 = __fmul_rn(__fmul_rn(d0.z, dx), dx);
            float t2 = __fmul_rn(__fmul_rn(d1.x, dy), dy);
            float sigma = __fadd_rn(__fmul_rn(0.5f, __fadd_rn(t1, t2)),
                                    __fmul_rn(__fmul_rn(d0.w, dx), dy));
            bool v = act && sigma >= 0.f && sigma <= 5.55f;  // e^-5.55 < 1/255
            float al = v ? fminf(__fmul_rn(d1.y, __expf(-sigma)), 0.999f) : 0.f;
            valid[k] = v && (al >= ALPHA_T);
            alpha[k] = al;
            colR[k] = d1.z; colG[k] = d1.w; colB[k] = s_d2[ii];
        }
        // phase 2: serial front-to-back blend (exact reference semantics)
        #pragma unroll
        for (int k = 0; k < 8; ++k) {
            if (valid[k] && !done) {
                float al = alpha[k];
                if (T > EPS_T) {
                    float w = __fmul_rn(T, al);
                    accR += w * colR[k];
                    accG += w * colG[k];
                    accB += w * colB[k];
                }
                T = __fmul_rn(T, __fsub_rn(1.f, al));
                count++;
                if (count >= FRONT_K || T <= EPS_T) done = true;
            }
        }
    }

    int o = ((b * HN + (ty0 + ly)) * WN + (tx0 + lx)) * 3;
    out[o] = accR;
    out[o + 1] = accG;
    out[o + 2] = accB;     // bg == 0, so output is accum only
}

extern "C" void kernel_launch(void* const* d_in, const int* in_sizes, int n_in,
                              void* d_out, int out_size, void* d_ws, size_t ws_size,
                              hipStream_t stream) {
    const float* means2d = (const float*)d_in[0];
    const float* conics  = (const float*)d_in[1];
    const float* colors  = (const float*)d_in[2];
    const float* opac    = (const float*)d_in[3];
    const float* depths  = (const float*)d_in[4];
    float* out = (float*)d_out;

    const int BG = BN * GN;
    float4*             dat0 = (float4*)d_ws;                      // 256 KB
    float4*             dat1 = dat0 + BG;                          // 256 KB
    float*              dat2 = (float*)(dat1 + BG);                //  64 KB
    unsigned long long* kdat = (unsigned long long*)(dat2 + BG);   // 128 KB
    unsigned*           cur  = (unsigned*)(kdat + BG);             //   8 KB
    unsigned*           ent  = cur + BN * NTILE;                   //   2 MB

    pgr_clear<<<(BN * NTILE) / 64, 64, 0, stream>>>(cur);
    pgr_prep<<<(BN * GN) / 8, 64, 0, stream>>>(means2d, conics, colors, opac,
                                               depths, dat0, dat1, dat2, kdat,
                                               cur, ent);
    pgr_raster<<<dim3(TDIM, TDIM, BN), 256, 0, stream>>>(
        dat0, dat1, dat2, kdat, cur, ent, out);
}